// Round 6
// baseline (716.991 us; speedup 1.0000x reference)
//
#include <hip/hip_runtime.h>
#include <cstdint>

typedef __bf16 bf16;
typedef bf16 bf16x8 __attribute__((ext_vector_type(8)));
typedef float f32x4 __attribute__((ext_vector_type(4)));

#define S_LEN   16384
#define HID     1280
#define NHEAD   16
#define HD      80
#define HDP     96
#define CHUNK   1024
#define NCHUNKS 16

// workspace element offsets (bf16 elements)
#define OFF_XB     0LL           // x bf16            [16384][1280]
#define OFF_WQKV   20971520LL    // w_qkv bf16        [3840][1280]
#define OFF_WPROJ  25886720LL    // w_proj bf16       [1280][1280]
#define OFF_QPAD   27525120LL    // q bf16 padded     [16384][16][96]
#define OFF_KPAD   52690944LL    // k bf16 padded     [16384][16][96]
#define OFF_VT     77856768LL    // v^T bf16          [16][16][80][1024]
#define OFF_ATTN   98828288LL    // attn out bf16     [16384][1280]

// global -> LDS direct copy, 16 B per lane; lane i lands at base + i*16.
__device__ __forceinline__ void gl_lds16(const void* g, void* l) {
  __builtin_amdgcn_global_load_lds(
      (const __attribute__((address_space(1))) unsigned int*)g,
      (__attribute__((address_space(3))) unsigned int*)l, 16, 0, 0);
}

// ---------------------------------------------------------------------------
// Kernel 1: fp32 -> bf16 conversion + zero-fill of q/k pad dims (80..95)
// ---------------------------------------------------------------------------
__global__ void convert_kernel(const float* __restrict__ x,
                               const float* __restrict__ wqkv,
                               const float* __restrict__ wproj,
                               bf16* __restrict__ ws) {
  const long long N1 = 20971520LL;
  const long long N2 = 4915200LL;
  const long long N3 = 1638400LL;
  const long long N4 = 4194304LL;
  long long i = ((long long)blockIdx.x * 256 + threadIdx.x) << 2;
  if (i < N1) {
    float4 v = *(const float4*)(x + i);
    bf16* o = ws + OFF_XB + i;
    o[0] = (bf16)v.x; o[1] = (bf16)v.y; o[2] = (bf16)v.z; o[3] = (bf16)v.w;
    return;
  }
  i -= N1;
  if (i < N2) {
    float4 v = *(const float4*)(wqkv + i);
    bf16* o = ws + OFF_WQKV + i;
    o[0] = (bf16)v.x; o[1] = (bf16)v.y; o[2] = (bf16)v.z; o[3] = (bf16)v.w;
    return;
  }
  i -= N2;
  if (i < N3) {
    float4 v = *(const float4*)(wproj + i);
    bf16* o = ws + OFF_WPROJ + i;
    o[0] = (bf16)v.x; o[1] = (bf16)v.y; o[2] = (bf16)v.z; o[3] = (bf16)v.w;
    return;
  }
  i -= N3;
  if (i < N4) {
    long long g = i >> 4; int j = (int)(i & 15);
    *(uint2*)(ws + OFF_QPAD + g * HDP + HD + j) = make_uint2(0u, 0u);
    return;
  }
  i -= N4;
  if (i < N4) {
    long long g = i >> 4; int j = (int)(i & 15);
    *(uint2*)(ws + OFF_KPAD + g * HDP + HD + j) = make_uint2(0u, 0u);
    return;
  }
}

// ---------------------------------------------------------------------------
// Kernels 2 & 5: bf16 GEMM C = A @ B^T (+bias) — round-6: 256x256 tile.
// THEORY (rounds 0-5): throughput was pinned at ~640 TF in every structure
// because perf = staging-intensity x DMA-rate: the global_load_lds path
// sustains only ~7-9.4 TB/s chip-wide, and every prior tile had
// BM*BN/(BM+BN) = 64-85 FLOP/staged-byte.  This kernel doubles intensity
// to 128 (256^2) while keeping the multi-block DMA concurrency that r5
// showed drives the DMA hardest:
//   - 512 thr / 8 waves (2M x 4N), wave-tile 128x64, acc[8][4]
//     (fragment/epilogue code refchecked in rounds 1-3).
//   - BK=32, plain double-buffer, 2 x 32 KB LDS = 64 KB -> 2 blocks/CU.
//   - r5's plain __syncthreads-per-step schedule (empirically the best
//     DMA throughput; fancy vmcnt schedules all regressed).
//   - staging 4 x gl_lds16 per thread per step; read-slot swizzle
//     slot = quad ^ ((l16>>2)&3), staging-side inverse k-group on the
//     per-lane GLOBAL address (LDS dest linear, refchecked r2).
// Grids: g0 (64,15)=960 blocks, g1 (64,5)=320 (all resident at 2/CU).
// blockIdx.x = M-fast: same-A-strip blocks have ids congruent mod 8 ->
// same XCD L2.
// ---------------------------------------------------------------------------
template <int MODE>
__global__ __launch_bounds__(512, 2) void gemm_bt_kernel(
    const bf16* __restrict__ A, const bf16* __restrict__ B,
    const float* __restrict__ bias, bf16* __restrict__ ws,
    float* __restrict__ outF) {
  __shared__ __align__(16) bf16 AB[2][16384];  // 32 KB per buffer: A 16K, B 16K

  const int tid = threadIdx.x;
  const int lane = tid & 63;
  const int w = tid >> 6;                 // 0..7
  const int wm = w >> 2, wn = w & 3;      // wave row (0,1) / col (0..3)
  const int quad = lane >> 4, l16 = lane & 15;
  const long long m0 = (long long)blockIdx.x * 256;
  const long long n0 = (long long)blockIdx.y * 256;

  // staging: chunk ci = j*512 + tid (j=0,1 per operand); row = ci>>2
  // (0..255), slot = ci&3.  LDS slot stores k-group (slot ^ ((row>>2)&3)):
  // (row>>2)&3 == (tid>>4)&3 for both j (j=1 row offset 128 = 0 mod 4).
  const int r0 = tid >> 2;
  const int kg = (tid & 3) ^ ((tid >> 4) & 3);
  const long long off0 = (long long)r0 * 1280 + (kg << 3);
  const bf16* srcA = A + m0 * 1280 + off0;   // j=1 source: +128 rows = +163840
  const bf16* srcB = B + n0 * 1280 + off0;

  // fragment read bases (byte): row*64 + swizzled 16-B slot
  const int rbA = (wm * 128 + l16) * 64;
  const int rbB = (wn * 64 + l16) * 64;
  const int csw = (quad ^ ((l16 >> 2) & 3)) << 4;

  f32x4 acc[8][4] = {};

  // prologue: stage step 0 into buffer 0
  {
    char* d = (char*)AB[0] + tid * 16;
    gl_lds16(srcA, d);            gl_lds16(srcA + 163840, d + 8192);
    gl_lds16(srcB, d + 16384);    gl_lds16(srcB + 163840, d + 24576);
  }

  for (int k0 = 0; k0 < 40; ++k0) {
    const int cur = k0 & 1;
    __syncthreads();  // drains vmcnt -> buf[cur] ready; buf[cur^1] free
    if (k0 + 1 < 40) {
      const bf16* sA = srcA + (k0 + 1) * 32;
      const bf16* sB = srcB + (k0 + 1) * 32;
      char* d = (char*)AB[cur ^ 1] + tid * 16;
      gl_lds16(sA, d);            gl_lds16(sA + 163840, d + 8192);
      gl_lds16(sB, d + 16384);    gl_lds16(sB + 163840, d + 24576);
    }
    const char* buf = (const char*)AB[cur];
    bf16x8 af[8], bfr[4];
#pragma unroll
    for (int it = 0; it < 8; ++it)
      af[it] = *(const bf16x8*)(buf + rbA + it * 1024 + csw);
#pragma unroll
    for (int jt = 0; jt < 4; ++jt)
      bfr[jt] = *(const bf16x8*)(buf + 16384 + rbB + jt * 1024 + csw);
#pragma unroll
    for (int it = 0; it < 8; ++it)
#pragma unroll
      for (int jt = 0; jt < 4; ++jt)
        acc[it][jt] = __builtin_amdgcn_mfma_f32_16x16x32_bf16(
            af[it], bfr[jt], acc[it][jt], 0, 0, 0);
  }

  // ---- epilogue (refchecked rounds 1-3) ----
  if (MODE == 0) {
    bf16* qpad = ws + OFF_QPAD;
    bf16* kpad = ws + OFF_KPAD;
    bf16* vt = ws + OFF_VT;
#pragma unroll
    for (int jt = 0; jt < 4; ++jt) {
      int n = (int)n0 + wn * 64 + jt * 16 + l16;
      float bv = bias[n];
      int part = n / HID;
      int idx = n - part * HID;
      int h = idx / HD;
      int d = idx - h * HD;
#pragma unroll
      for (int it = 0; it < 8; ++it) {
#pragma unroll
        for (int r = 0; r < 4; ++r) {
          long long m = m0 + wm * 128 + it * 16 + quad * 4 + r;
          float v = acc[it][jt][r] + bv;
          if (part == 0) {
            qpad[(m * NHEAD + h) * HDP + d] = (bf16)v;
          } else if (part == 1) {
            kpad[(m * NHEAD + h) * HDP + d] = (bf16)v;
          } else {
            long long c = m >> 10, t2 = m & 1023;
            vt[((c * NHEAD + h) * HD + d) * CHUNK + t2] = (bf16)v;
          }
        }
      }
    }
  } else {
#pragma unroll
    for (int jt = 0; jt < 4; ++jt) {
      int n = (int)n0 + wn * 64 + jt * 16 + l16;
      float bv = bias[n];
#pragma unroll
      for (int it = 0; it < 8; ++it) {
#pragma unroll
        for (int r = 0; r < 4; ++r) {
          long long m = m0 + wm * 128 + it * 16 + quad * 4 + r;
          outF[m * HID + n] = acc[it][jt][r] + bv;
        }
      }
    }
  }
}

// ---------------------------------------------------------------------------
// Kernel 3: RoPE in-place, vectorized bf16x8.
// ---------------------------------------------------------------------------
__global__ void rope_kernel(const float* __restrict__ cosp,
                            const float* __restrict__ sinp,
                            bf16* __restrict__ ws) {
  long long i = (long long)blockIdx.x * 256 + threadIdx.x;
  int g = (int)(i % 5);
  long long r = i / 5;
  int h = (int)(r % NHEAD);
  long long r2 = r / NHEAD;
  int tok = (int)(r2 % S_LEN);
  int isK = (int)(r2 / S_LEN);
  bf16* base = ws + (isK ? OFF_KPAD : OFF_QPAD) + ((long long)tok * NHEAD + h) * HDP;
  bf16x8 a8 = *(const bf16x8*)(base + g * 8);
  bf16x8 b8 = *(const bf16x8*)(base + 40 + g * 8);
  const float* cb = cosp + (long long)tok * HD;
  const float* sb = sinp + (long long)tok * HD;
  bf16x8 oA, oB;
#pragma unroll
  for (int j = 0; j < 8; ++j) {
    float a = (float)a8[j], b = (float)b8[j];
    int d = g * 8 + j;
    oA[j] = (bf16)(a * cb[d] - b * sb[d]);
    oB[j] = (bf16)(b * cb[d + 40] + a * sb[d + 40]);
  }
  *(bf16x8*)(base + g * 8) = oA;
  *(bf16x8*)(base + 40 + g * 8) = oB;
}

// ---------------------------------------------------------------------------
// Kernel 4: flash attention — 512 threads / 8 waves (round-4 version).
// Each wave owns 32 Q-rows (it=2). K-tile 64, double-buffered DMA staging,
// one barrier per tile. LDS 100 KB -> 1 block/CU, 8 waves = 2/SIMD.
// ---------------------------------------------------------------------------
__global__ __launch_bounds__(512, 1) void attn_kernel(bf16* __restrict__ ws) {
  __shared__ __align__(16) bf16 Ks[2][64 * 104];       // 13312 B each
  __shared__ __align__(16) bf16 Vs[2][80 * 88 + 128];  // 14336 B each
  __shared__ __align__(16) bf16 Ps[256 * 88];          // 45056 B
  const int ch = blockIdx.x;
  const int c = ch >> 4, h = ch & 15;
  const int qt = blockIdx.y;
  const int tid = threadIdx.x, lane = tid & 63, w = tid >> 6;
  const int quad = lane >> 4, l16 = lane & 15;

  const bf16* qpad = ws + OFF_QPAD;
  const bf16* kpad = ws + OFF_KPAD;
  const bf16* vt = ws + OFF_VT;
  bf16* attn = ws + OFF_ATTN;

  // --- staging source precompute (chunk ci = j*512 + tid) ---
  const char* kbase =
      (const char*)(kpad + (((long long)c * CHUNK) * NHEAD + h) * HDP);
  const char* ksrc[2];
#pragma unroll
  for (int j = 0; j < 2; ++j) {
    int ci = tid + j * 512;
    int ciq = ci < 832 ? ci : 831;
    int row = ciq / 13;
    int cb = (ciq - row * 13) * 16;
    if (cb >= 192) cb = 0;
    ksrc[j] = kbase + row * 3072 + cb;
  }
  const char* vbase = (const char*)(vt + ((long long)c * NHEAD + h) * HD * CHUNK);
  const char* vsrc[2];
#pragma unroll
  for (int j = 0; j < 2; ++j) {
    int ci = tid + j * 512;
    int row = ci / 11;
    if (row > 79) row = 79;
    int cb = (ci - row * 11) * 16;
    if (cb >= 128) cb = 0;
    vsrc[j] = vbase + row * 2048 + cb;
  }
  const int wb = w * 1024;

  // prologue: stage tile 0 into buffer 0
  {
    gl_lds16(ksrc[0], (char*)Ks[0] + wb);
    if (tid < 320) gl_lds16(ksrc[1], (char*)Ks[0] + 8192 + wb);
    gl_lds16(vsrc[0], (char*)Vs[0] + wb);
    if (tid < 368) gl_lds16(vsrc[1], (char*)Vs[0] + 8192 + wb);
  }

  // --- Q fragments, pre-scaled (overlaps the prologue DMA) ---
  const float scale = 0.111803398875f;  // 1/sqrt(80)
  bf16x8 qf[2][3];
#pragma unroll
  for (int it = 0; it < 2; ++it) {
    long long tok = (long long)c * CHUNK + qt * 256 + w * 32 + it * 16 + l16;
    const bf16* qrow = qpad + (tok * NHEAD + h) * HDP;
#pragma unroll
    for (int ks = 0; ks < 3; ++ks) {
      bf16x8 t = *(const bf16x8*)(qrow + ks * 32 + quad * 8);
#pragma unroll
      for (int j = 0; j < 8; ++j) t[j] = (bf16)((float)t[j] * scale);
      qf[it][ks] = t;
    }
  }

  f32x4 o[2][5] = {};
  float lrow[2][4] = {};

  for (int t = 0; t < 16; ++t) {
    const int cur = t & 1;
    __syncthreads();
    if (t + 1 < 16) {
      const int kadv = (t + 1) * 64 * 3072;
      const int vadv = (t + 1) * 64 * 2;
      gl_lds16(ksrc[0] + kadv, (char*)Ks[cur ^ 1] + wb);
      if (tid < 320) gl_lds16(ksrc[1] + kadv, (char*)Ks[cur ^ 1] + 8192 + wb);
      gl_lds16(vsrc[0] + vadv, (char*)Vs[cur ^ 1] + wb);
      if (tid < 368) gl_lds16(vsrc[1] + vadv, (char*)Vs[cur ^ 1] + 8192 + wb);
    }
    const bf16* K_ = Ks[cur];
    const bf16* V_ = Vs[cur];

    // S = Q K^T, exp, Ps write (wave-private rows w*32..w*32+31)
#pragma unroll
    for (int jt = 0; jt < 4; ++jt) {
      bf16x8 kb[3];
#pragma unroll
      for (int ks = 0; ks < 3; ++ks)
        kb[ks] = *(const bf16x8*)(K_ + (jt * 16 + l16) * 104 + ks * 32 + quad * 8);
#pragma unroll
      for (int it = 0; it < 2; ++it) {
        f32x4 z = {};
#pragma unroll
        for (int ks = 0; ks < 3; ++ks)
          z = __builtin_amdgcn_mfma_f32_16x16x32_bf16(qf[it][ks], kb[ks], z, 0, 0, 0);
#pragma unroll
        for (int r = 0; r < 4; ++r) {
          float p2 = __expf(z[r]);
          lrow[it][r] += p2;
          Ps[(w * 32 + it * 16 + quad * 4 + r) * 88 + jt * 16 + l16] = (bf16)p2;
        }
      }
    }

    // O += P V (Ps same-wave write->read; compiler inserts lgkmcnt wait)
#pragma unroll
    for (int k2 = 0; k2 < 2; ++k2) {
      bf16x8 pa[2];
#pragma unroll
      for (int it = 0; it < 2; ++it)
        pa[it] = *(const bf16x8*)(Ps + (w * 32 + it * 16 + l16) * 88 + k2 * 32 + quad * 8);
#pragma unroll
      for (int ct = 0; ct < 5; ++ct) {
        bf16x8 vb = *(const bf16x8*)(V_ + (ct * 16 + l16) * 88 + k2 * 32 + quad * 8);
#pragma unroll
        for (int it = 0; it < 2; ++it)
          o[it][ct] = __builtin_amdgcn_mfma_f32_16x16x32_bf16(pa[it], vb, o[it][ct], 0, 0, 0);
      }
    }
  }

  // final row-sum reduce (over l16) and write
#pragma unroll
  for (int it = 0; it < 2; ++it) {
#pragma unroll
    for (int r = 0; r < 4; ++r) {
      float l = lrow[it][r];
      l += __shfl_xor(l, 1, 64);
      l += __shfl_xor(l, 2, 64);
      l += __shfl_xor(l, 4, 64);
      l += __shfl_xor(l, 8, 64);
      float rinv = 1.0f / l;
      long long tok = (long long)c * CHUNK + qt * 256 + w * 32 + it * 16 + quad * 4 + r;
#pragma unroll
      for (int ct = 0; ct < 5; ++ct)
        attn[tok * HID + h * HD + ct * 16 + l16] = (bf16)(o[it][ct][r] * rinv);
    }
  }
}

// ---------------------------------------------------------------------------
extern "C" void kernel_launch(void* const* d_in, const int* in_sizes, int n_in,
                              void* d_out, int out_size, void* d_ws,
                              size_t ws_size, hipStream_t stream) {
  const float* x = (const float*)d_in[0];
  const float* cosp = (const float*)d_in[2];
  const float* sinp = (const float*)d_in[3];
  const float* wqkv = (const float*)d_in[4];
  const float* bqkv = (const float*)d_in[5];
  const float* wproj = (const float*)d_in[6];
  const float* bproj = (const float*)d_in[7];
  bf16* ws = (bf16*)d_ws;
  float* out = (float*)d_out;

  convert_kernel<<<35072, 256, 0, stream>>>(x, wqkv, wproj, ws);
  gemm_bt_kernel<0><<<dim3(64, 15), 512, 0, stream>>>(
      ws + OFF_XB, ws + OFF_WQKV, bqkv, ws, nullptr);
  rope_kernel<<<10240, 256, 0, stream>>>(cosp, sinp, ws);
  attn_kernel<<<dim3(256, 4), 512, 0, stream>>>(ws);
  gemm_bt_kernel<1><<<dim3(64, 5), 512, 0, stream>>>(
      ws + OFF_ATTN, ws + OFF_WPROJ, bproj, ws, out);
}

// Round 7
// 666.772 us; speedup vs baseline: 1.0753x; 1.0753x over previous
//
#include <hip/hip_runtime.h>
#include <cstdint>

typedef __bf16 bf16;
typedef bf16 bf16x8 __attribute__((ext_vector_type(8)));
typedef float f32x4 __attribute__((ext_vector_type(4)));

#define S_LEN   16384
#define HID     1280
#define NHEAD   16
#define HD      80
#define HDP     96
#define CHUNK   1024
#define NCHUNKS 16

// workspace element offsets (bf16 elements)
#define OFF_XB     0LL           // x bf16            [16384][1280]
#define OFF_WQKV   20971520LL    // w_qkv bf16        [3840][1280]
#define OFF_WPROJ  25886720LL    // w_proj bf16       [1280][1280]
#define OFF_QPAD   27525120LL    // q bf16 padded     [16384][16][96]
#define OFF_KPAD   52690944LL    // k bf16 padded     [16384][16][96]
#define OFF_VT     77856768LL    // v^T bf16          [16][16][80][1024]
#define OFF_ATTN   98828288LL    // attn out bf16     [16384][1280]

// global -> LDS direct copy, 16 B per lane; lane i lands at base + i*16.
__device__ __forceinline__ void gl_lds16(const void* g, void* l) {
  __builtin_amdgcn_global_load_lds(
      (const __attribute__((address_space(1))) unsigned int*)g,
      (__attribute__((address_space(3))) unsigned int*)l, 16, 0, 0);
}

// ---------------------------------------------------------------------------
// Kernel 1: fp32 -> bf16 conversion + zero-fill of q/k pad dims (80..95)
// ---------------------------------------------------------------------------
__global__ void convert_kernel(const float* __restrict__ x,
                               const float* __restrict__ wqkv,
                               const float* __restrict__ wproj,
                               bf16* __restrict__ ws) {
  const long long N1 = 20971520LL;
  const long long N2 = 4915200LL;
  const long long N3 = 1638400LL;
  const long long N4 = 4194304LL;
  long long i = ((long long)blockIdx.x * 256 + threadIdx.x) << 2;
  if (i < N1) {
    float4 v = *(const float4*)(x + i);
    bf16* o = ws + OFF_XB + i;
    o[0] = (bf16)v.x; o[1] = (bf16)v.y; o[2] = (bf16)v.z; o[3] = (bf16)v.w;
    return;
  }
  i -= N1;
  if (i < N2) {
    float4 v = *(const float4*)(wqkv + i);
    bf16* o = ws + OFF_WQKV + i;
    o[0] = (bf16)v.x; o[1] = (bf16)v.y; o[2] = (bf16)v.z; o[3] = (bf16)v.w;
    return;
  }
  i -= N2;
  if (i < N3) {
    float4 v = *(const float4*)(wproj + i);
    bf16* o = ws + OFF_WPROJ + i;
    o[0] = (bf16)v.x; o[1] = (bf16)v.y; o[2] = (bf16)v.z; o[3] = (bf16)v.w;
    return;
  }
  i -= N3;
  if (i < N4) {
    long long g = i >> 4; int j = (int)(i & 15);
    *(uint2*)(ws + OFF_QPAD + g * HDP + HD + j) = make_uint2(0u, 0u);
    return;
  }
  i -= N4;
  if (i < N4) {
    long long g = i >> 4; int j = (int)(i & 15);
    *(uint2*)(ws + OFF_KPAD + g * HDP + HD + j) = make_uint2(0u, 0u);
    return;
  }
}

// ---------------------------------------------------------------------------
// Kernels 2 & 5: bf16 GEMM C = A @ B^T (+bias) — round-5 config (parked).
// Six structural variants (rounds 0-6) all land at ~16 cyc/MFMA/CU = 610-640
// TF; this 128x128 / 4-blocks-per-CU version gave the best total.
// ---------------------------------------------------------------------------
template <int MODE>
__global__ __launch_bounds__(256, 4) void gemm_bt_kernel(
    const bf16* __restrict__ A, const bf16* __restrict__ B,
    const float* __restrict__ bias, bf16* __restrict__ ws,
    float* __restrict__ outF) {
  __shared__ __align__(16) bf16 AB[2][8192];  // 16 KB per buffer

  const int tid = threadIdx.x;
  const int lane = tid & 63;
  const int w = tid >> 6;                 // 0..3
  const int wr = w >> 1, wc = w & 1;      // wave row / col
  const int quad = lane >> 4, l16 = lane & 15;
  const long long m0 = (long long)blockIdx.x * 128;
  const long long n0 = (long long)blockIdx.y * 128;

  const int r0 = tid >> 2;
  const int kg = (tid & 3) ^ ((tid >> 4) & 3);
  const long long off0 = (long long)r0 * 1280 + (kg << 3);
  const bf16* srcA = A + m0 * 1280 + off0;   // j=1 source: +64 rows = +81920
  const bf16* srcB = B + n0 * 1280 + off0;

  const int rbA = (wr * 64 + l16) * 64;
  const int rbB = (wc * 64 + l16) * 64;
  const int csw = (quad ^ ((l16 >> 2) & 3)) << 4;

  f32x4 acc[4][4] = {};

  // prologue: stage step 0 into buffer 0
  {
    char* d = (char*)AB[0] + tid * 16;
    gl_lds16(srcA, d);           gl_lds16(srcA + 81920, d + 4096);
    gl_lds16(srcB, d + 8192);    gl_lds16(srcB + 81920, d + 12288);
  }

  for (int k0 = 0; k0 < 40; ++k0) {
    const int cur = k0 & 1;
    __syncthreads();  // drains vmcnt -> buf[cur] ready; buf[cur^1] free
    if (k0 + 1 < 40) {
      const bf16* sA = srcA + (k0 + 1) * 32;
      const bf16* sB = srcB + (k0 + 1) * 32;
      char* d = (char*)AB[cur ^ 1] + tid * 16;
      gl_lds16(sA, d);           gl_lds16(sA + 81920, d + 4096);
      gl_lds16(sB, d + 8192);    gl_lds16(sB + 81920, d + 12288);
    }
    const char* buf = (const char*)AB[cur];
    bf16x8 af[4], bfr[4];
#pragma unroll
    for (int it = 0; it < 4; ++it)
      af[it] = *(const bf16x8*)(buf + rbA + it * 1024 + csw);
#pragma unroll
    for (int jt = 0; jt < 4; ++jt)
      bfr[jt] = *(const bf16x8*)(buf + 8192 + rbB + jt * 1024 + csw);
#pragma unroll
    for (int it = 0; it < 4; ++it)
#pragma unroll
      for (int jt = 0; jt < 4; ++jt)
        acc[it][jt] = __builtin_amdgcn_mfma_f32_16x16x32_bf16(
            af[it], bfr[jt], acc[it][jt], 0, 0, 0);
  }

  // ---- epilogue ----
  if (MODE == 0) {
    bf16* qpad = ws + OFF_QPAD;
    bf16* kpad = ws + OFF_KPAD;
    bf16* vt = ws + OFF_VT;
#pragma unroll
    for (int jt = 0; jt < 4; ++jt) {
      int n = (int)n0 + wc * 64 + jt * 16 + l16;
      float bv = bias[n];
      int part = n / HID;
      int idx = n - part * HID;
      int h = idx / HD;
      int d = idx - h * HD;
#pragma unroll
      for (int it = 0; it < 4; ++it) {
#pragma unroll
        for (int r = 0; r < 4; ++r) {
          long long m = m0 + wr * 64 + it * 16 + quad * 4 + r;
          float v = acc[it][jt][r] + bv;
          if (part == 0) {
            qpad[(m * NHEAD + h) * HDP + d] = (bf16)v;
          } else if (part == 1) {
            kpad[(m * NHEAD + h) * HDP + d] = (bf16)v;
          } else {
            long long c = m >> 10, t2 = m & 1023;
            vt[((c * NHEAD + h) * HD + d) * CHUNK + t2] = (bf16)v;
          }
        }
      }
    }
  } else {
#pragma unroll
    for (int jt = 0; jt < 4; ++jt) {
      int n = (int)n0 + wc * 64 + jt * 16 + l16;
      float bv = bias[n];
#pragma unroll
      for (int it = 0; it < 4; ++it) {
#pragma unroll
        for (int r = 0; r < 4; ++r) {
          long long m = m0 + wr * 64 + it * 16 + quad * 4 + r;
          outF[m * HID + n] = acc[it][jt][r] + bv;
        }
      }
    }
  }
}

// ---------------------------------------------------------------------------
// Kernel 3: RoPE in-place, vectorized bf16x8.
// ---------------------------------------------------------------------------
__global__ void rope_kernel(const float* __restrict__ cosp,
                            const float* __restrict__ sinp,
                            bf16* __restrict__ ws) {
  long long i = (long long)blockIdx.x * 256 + threadIdx.x;
  int g = (int)(i % 5);
  long long r = i / 5;
  int h = (int)(r % NHEAD);
  long long r2 = r / NHEAD;
  int tok = (int)(r2 % S_LEN);
  int isK = (int)(r2 / S_LEN);
  bf16* base = ws + (isK ? OFF_KPAD : OFF_QPAD) + ((long long)tok * NHEAD + h) * HDP;
  bf16x8 a8 = *(const bf16x8*)(base + g * 8);
  bf16x8 b8 = *(const bf16x8*)(base + 40 + g * 8);
  const float* cb = cosp + (long long)tok * HD;
  const float* sb = sinp + (long long)tok * HD;
  bf16x8 oA, oB;
#pragma unroll
  for (int j = 0; j < 8; ++j) {
    float a = (float)a8[j], b = (float)b8[j];
    int d = g * 8 + j;
    oA[j] = (bf16)(a * cb[d] - b * sb[d]);
    oB[j] = (bf16)(b * cb[d + 40] + a * sb[d + 40]);
  }
  *(bf16x8*)(base + g * 8) = oA;
  *(bf16x8*)(base + 40 + g * 8) = oB;
}

// ---------------------------------------------------------------------------
// Kernel 4: flash attention — round-7: 2 blocks/CU + zero-exposed-DMA
// schedule.  Diagnosis: attn was ~250 µs hiding under the top-5 cutoff, at
// 1 block/CU (100 KB LDS) with full per-tile latency exposure.  Changes:
//   - LDS 100 -> 77 KB: Ps stride 88->72 (36.9 KB; row stride 144 B == 16
//     mod 128 -> 2-way bank alias only, free per m136), K SINGLE-buffered
//     (13 KB), V double-buffered (28.7 KB)  => 2 blocks/CU.
//   - Tile loop: b1 = __syncthreads (drains K(t)/V(t) DMA) -> V(t+1)
//     prefetch (dbuf; overwrites V[cur^1] last read pre-b1) -> QK^T +
//     softmax + Ps write (covers V issue) -> b2 = raw s_barrier (no vmem
//     drain needed: all K reads are consumed in MFMAs before any wave
//     reaches b2; sched_barrier fences motion) -> K(t+1) stage into the
//     single K buffer (covered by PV) -> PV.  Both DMAs drain at b1(t+1).
//   - __launch_bounds__(512,4): cap VGPR 128 for 2-block residency.
// ---------------------------------------------------------------------------
__global__ __launch_bounds__(512, 4) void attn_kernel(bf16* __restrict__ ws) {
  __shared__ __align__(16) bf16 Ks[64 * 104];          // 13312 B (single)
  __shared__ __align__(16) bf16 Vs[2][80 * 88 + 128];  // 14336 B each
  __shared__ __align__(16) bf16 Ps[256 * 72];          // 36864 B
  const int ch = blockIdx.x;
  const int c = ch >> 4, h = ch & 15;
  const int qt = blockIdx.y;
  const int tid = threadIdx.x, lane = tid & 63, w = tid >> 6;
  const int quad = lane >> 4, l16 = lane & 15;

  const bf16* qpad = ws + OFF_QPAD;
  const bf16* kpad = ws + OFF_KPAD;
  const bf16* vt = ws + OFF_VT;
  bf16* attn = ws + OFF_ATTN;

  // --- staging source precompute (chunk ci = j*512 + tid) ---
  const char* kbase =
      (const char*)(kpad + (((long long)c * CHUNK) * NHEAD + h) * HDP);
  const char* ksrc[2];
#pragma unroll
  for (int j = 0; j < 2; ++j) {
    int ci = tid + j * 512;
    int ciq = ci < 832 ? ci : 831;
    int row = ciq / 13;
    int cb = (ciq - row * 13) * 16;
    if (cb >= 192) cb = 0;
    ksrc[j] = kbase + row * 3072 + cb;
  }
  const char* vbase = (const char*)(vt + ((long long)c * NHEAD + h) * HD * CHUNK);
  const char* vsrc[2];
#pragma unroll
  for (int j = 0; j < 2; ++j) {
    int ci = tid + j * 512;
    int row = ci / 11;
    if (row > 79) row = 79;
    int cb = (ci - row * 11) * 16;
    if (cb >= 128) cb = 0;
    vsrc[j] = vbase + row * 2048 + cb;
  }
  const int wb = w * 1024;

  // prologue: stage tile 0 (K -> Ks single, V -> Vs[0])
  {
    gl_lds16(ksrc[0], (char*)Ks + wb);
    if (tid < 320) gl_lds16(ksrc[1], (char*)Ks + 8192 + wb);
    gl_lds16(vsrc[0], (char*)Vs[0] + wb);
    if (tid < 368) gl_lds16(vsrc[1], (char*)Vs[0] + 8192 + wb);
  }

  // --- Q fragments, pre-scaled (overlaps the prologue DMA) ---
  const float scale = 0.111803398875f;  // 1/sqrt(80)
  bf16x8 qf[2][3];
#pragma unroll
  for (int it = 0; it < 2; ++it) {
    long long tok = (long long)c * CHUNK + qt * 256 + w * 32 + it * 16 + l16;
    const bf16* qrow = qpad + (tok * NHEAD + h) * HDP;
#pragma unroll
    for (int ks = 0; ks < 3; ++ks) {
      bf16x8 t = *(const bf16x8*)(qrow + ks * 32 + quad * 8);
#pragma unroll
      for (int j = 0; j < 8; ++j) t[j] = (bf16)((float)t[j] * scale);
      qf[it][ks] = t;
    }
  }

  f32x4 o[2][5] = {};
  float lrow[2][4] = {};

  for (int t = 0; t < 16; ++t) {
    const int cur = t & 1;
    __syncthreads();  // b1: K(t) in Ks, V(t) in Vs[cur] (vmcnt drained)

    // V(t+1) prefetch into Vs[cur^1] (last read pre-b1; issue covered by QK^T)
    if (t + 1 < 16) {
      const int vadv = (t + 1) * 64 * 2;
      gl_lds16(vsrc[0] + vadv, (char*)Vs[cur ^ 1] + wb);
      if (tid < 368) gl_lds16(vsrc[1] + vadv, (char*)Vs[cur ^ 1] + 8192 + wb);
    }

    // S = Q K^T, exp, Ps write (wave-private rows w*32..w*32+31)
#pragma unroll
    for (int jt = 0; jt < 4; ++jt) {
      bf16x8 kb[3];
#pragma unroll
      for (int ks = 0; ks < 3; ++ks)
        kb[ks] = *(const bf16x8*)(Ks + (jt * 16 + l16) * 104 + ks * 32 + quad * 8);
#pragma unroll
      for (int it = 0; it < 2; ++it) {
        f32x4 z = {};
#pragma unroll
        for (int ks = 0; ks < 3; ++ks)
          z = __builtin_amdgcn_mfma_f32_16x16x32_bf16(qf[it][ks], kb[ks], z, 0, 0, 0);
#pragma unroll
        for (int r = 0; r < 4; ++r) {
          float p2 = __expf(z[r]);
          lrow[it][r] += p2;
          Ps[(w * 32 + it * 16 + quad * 4 + r) * 72 + jt * 16 + l16] = (bf16)p2;
        }
      }
    }

    // b2: all waves have CONSUMED their K reads (MFMA operands) before here;
    // raw barrier (no vmem drain) so the V prefetch stays in flight.
    __builtin_amdgcn_sched_barrier(0);
    __builtin_amdgcn_s_barrier();
    __builtin_amdgcn_sched_barrier(0);

    // K(t+1) stage into the single Ks buffer (covered by PV below)
    if (t + 1 < 16) {
      const int kadv = (t + 1) * 64 * 3072;
      gl_lds16(ksrc[0] + kadv, (char*)Ks + wb);
      if (tid < 320) gl_lds16(ksrc[1] + kadv, (char*)Ks + 8192 + wb);
    }

    // O += P V (Ps same-wave write->read; compiler inserts lgkmcnt wait)
    const bf16* V_ = Vs[cur];
#pragma unroll
    for (int k2 = 0; k2 < 2; ++k2) {
      bf16x8 pa[2];
#pragma unroll
      for (int it = 0; it < 2; ++it)
        pa[it] = *(const bf16x8*)(Ps + (w * 32 + it * 16 + l16) * 72 + k2 * 32 + quad * 8);
#pragma unroll
      for (int ct = 0; ct < 5; ++ct) {
        bf16x8 vb = *(const bf16x8*)(V_ + (ct * 16 + l16) * 88 + k2 * 32 + quad * 8);
#pragma unroll
        for (int it = 0; it < 2; ++it)
          o[it][ct] = __builtin_amdgcn_mfma_f32_16x16x32_bf16(pa[it], vb, o[it][ct], 0, 0, 0);
      }
    }
  }

  // final row-sum reduce (over l16) and write
#pragma unroll
  for (int it = 0; it < 2; ++it) {
#pragma unroll
    for (int r = 0; r < 4; ++r) {
      float l = lrow[it][r];
      l += __shfl_xor(l, 1, 64);
      l += __shfl_xor(l, 2, 64);
      l += __shfl_xor(l, 4, 64);
      l += __shfl_xor(l, 8, 64);
      float rinv = 1.0f / l;
      long long tok = (long long)c * CHUNK + qt * 256 + w * 32 + it * 16 + quad * 4 + r;
#pragma unroll
      for (int ct = 0; ct < 5; ++ct)
        attn[tok * HID + h * HD + ct * 16 + l16] = (bf16)(o[it][ct][r] * rinv);
    }
  }
}

// ---------------------------------------------------------------------------
extern "C" void kernel_launch(void* const* d_in, const int* in_sizes, int n_in,
                              void* d_out, int out_size, void* d_ws,
                              size_t ws_size, hipStream_t stream) {
  const float* x = (const float*)d_in[0];
  const float* cosp = (const float*)d_in[2];
  const float* sinp = (const float*)d_in[3];
  const float* wqkv = (const float*)d_in[4];
  const float* bqkv = (const float*)d_in[5];
  const float* wproj = (const float*)d_in[6];
  const float* bproj = (const float*)d_in[7];
  bf16* ws = (bf16*)d_ws;
  float* out = (float*)d_out;

  convert_kernel<<<35072, 256, 0, stream>>>(x, wqkv, wproj, ws);
  gemm_bt_kernel<0><<<dim3(128, 30), 256, 0, stream>>>(
      ws + OFF_XB, ws + OFF_WQKV, bqkv, ws, nullptr);
  rope_kernel<<<10240, 256, 0, stream>>>(cosp, sinp, ws);
  attn_kernel<<<dim3(256, 4), 512, 0, stream>>>(ws);
  gemm_bt_kernel<1><<<dim3(128, 10), 256, 0, stream>>>(
      ws + OFF_ATTN, ws + OFF_WPROJ, bproj, ws, out);
}